// Round 15
// baseline (122.787 us; speedup 1.0000x reference)
//
#include <hip/hip_runtime.h>
#include <cstdint>
#include <cstddef>

#define DD    2048
#define NE    8
#define NTOK  4096
#define CAP   512
#define TPB   4                       // tokens per k_finish block
#define NFB   (NTOK / TPB)            // 1024 finish blocks
#define NLB   (NTOK / 2)              // 2048 logits blocks (2 tokens each)
#define DISP_ELEMS (NTOK * NE * CAP)  // 16,777,216 floats
#define GATES_OFF  DISP_ELEMS
#define IDX_OFF    (DISP_ELEMS + NTOK * 2)
#define SLICE      (TPB * NE * CAP)   // 16384 floats = 64 KB per finish block

// ---------------------------------------------------------------------------
// k_logits3: 2048 blocks x 256. Block b: tokens {2b, 2b+1}.
// Wave w: token 2b + (w&1), experts (w>>1)*4 .. +3 (acc[4] f64 per lane).
// Lane covers dims kk*512 + lane*8 .. +7 for kk = 0..3:
//   x:  2 float4 per pass, contiguous 2 KB per wave per pass.
//   W:  W[d][eh*4..+3] is ONE float4 at f4-index d*2+eh — natural layout,
//       no transpose, no scalar loads (fixes R7's stride-32B scalar W reads).
// 40 loads/lane, 128 f64 FMA, 24 f64 shfl reduce -> shallow per-wave chain;
// 8192 waves chip-wide hide HBM latency by TLP (fixes R8's 26% occupancy).
// One barrier to combine the two expert halves; threads 0-1 finalize.
// ---------------------------------------------------------------------------
__global__ __launch_bounds__(256) void k_logits3(
    const float* __restrict__ x, const float* __restrict__ W,
    float* __restrict__ out, int2* __restrict__ choices)
{
    const int tid  = threadIdx.x;
    const int bid  = blockIdx.x;
    const int wv   = tid >> 6;        // 0..3
    const int lane = tid & 63;
    const int n    = bid * 2 + (wv & 1);
    const int eh   = wv >> 1;         // expert half: 0 -> 0..3, 1 -> 4..7

    const float4* x4 = reinterpret_cast<const float4*>(x) + (size_t)n * (DD / 4);
    const float4* W4 = reinterpret_cast<const float4*>(W);

    double acc0 = 0.0, acc1 = 0.0, acc2 = 0.0, acc3 = 0.0;

#define ACC4(XD, WV) { acc0 += (double)(XD) * (double)(WV).x; \
                       acc1 += (double)(XD) * (double)(WV).y; \
                       acc2 += (double)(XD) * (double)(WV).z; \
                       acc3 += (double)(XD) * (double)(WV).w; }

    #pragma unroll
    for (int kk = 0; kk < 4; ++kk) {
        const int dbase = kk * 512 + lane * 8;
        float4 xa = x4[kk * 128 + lane * 2];
        float4 xb = x4[kk * 128 + lane * 2 + 1];
        float4 w0 = W4[(size_t)(dbase + 0) * 2 + eh];
        float4 w1 = W4[(size_t)(dbase + 1) * 2 + eh];
        float4 w2 = W4[(size_t)(dbase + 2) * 2 + eh];
        float4 w3 = W4[(size_t)(dbase + 3) * 2 + eh];
        float4 w4 = W4[(size_t)(dbase + 4) * 2 + eh];
        float4 w5 = W4[(size_t)(dbase + 5) * 2 + eh];
        float4 w6 = W4[(size_t)(dbase + 6) * 2 + eh];
        float4 w7 = W4[(size_t)(dbase + 7) * 2 + eh];
        ACC4(xa.x, w0) ACC4(xa.y, w1) ACC4(xa.z, w2) ACC4(xa.w, w3)
        ACC4(xb.x, w4) ACC4(xb.y, w5) ACC4(xb.z, w6) ACC4(xb.w, w7)
    }
#undef ACC4

    #pragma unroll
    for (int off = 1; off < 64; off <<= 1) {
        acc0 += __shfl_xor(acc0, off, 64);
        acc1 += __shfl_xor(acc1, off, 64);
        acc2 += __shfl_xor(acc2, off, 64);
        acc3 += __shfl_xor(acc3, off, 64);
    }

    __shared__ double redbuf[2][NE];
    if (lane == 0) {
        redbuf[wv & 1][eh * 4 + 0] = acc0;
        redbuf[wv & 1][eh * 4 + 1] = acc1;
        redbuf[wv & 1][eh * 4 + 2] = acc2;
        redbuf[wv & 1][eh * 4 + 3] = acc3;
    }
    __syncthreads();

    if (tid < 2) {
        const int nn = bid * 2 + tid;
        float lg[NE];
        #pragma unroll
        for (int q = 0; q < NE; ++q) lg[q] = (float)redbuf[tid][q];

        int e0 = 0;
        #pragma unroll
        for (int q = 1; q < NE; ++q) if (lg[q] > lg[e0]) e0 = q;
        int e1 = -1;
        #pragma unroll
        for (int q = 0; q < NE; ++q) {
            if (q == e0) continue;
            if (e1 < 0 || lg[q] > lg[e1]) e1 = q;
        }

        float p1 = __expf(lg[e1] - lg[e0]);    // lg[e0] >= lg[e1]
        float s  = 1.0f + p1;
        out[GATES_OFF + nn * 2 + 0] = 1.0f / s;
        out[GATES_OFF + nn * 2 + 1] = p1 / s;
        out[IDX_OFF   + nn * 2 + 0] = (float)e0;
        out[IDX_OFF   + nn * 2 + 1] = (float)e1;
        int2 c; c.x = e0; c.y = e1;
        choices[nn] = c;
    }
}

// ---------------------------------------------------------------------------
// k_finish: 1024 blocks x 256 (R7's proven zero+patch structure; phase A now
// scans choices directly — no hist array).
//   A) per-thread register histogram over tokens < bid*4 (coalesced int2
//      reads, L2-hot 32 KB), wave butterfly, LDS combine -> base[16].
//   B) thread 0: in-block ranks for its 4 tokens -> <=8 targets.
//   C) zero its 64 KB dispatcher slice, barrier, patch 1.0f.
// ---------------------------------------------------------------------------
__global__ __launch_bounds__(256) void k_finish(
    const int2* __restrict__ choices, float* __restrict__ out)
{
    __shared__ unsigned partial[4][16];
    __shared__ unsigned base[16];
    __shared__ int tg[TPB * 2];

    const int tid  = threadIdx.x;
    const int bid  = blockIdx.x;
    const int lane = tid & 63;
    const int wv   = tid >> 6;

    // ---- A: register histogram over preceding tokens --------------------
    unsigned cnt[16];
    #pragma unroll
    for (int p = 0; p < 16; ++p) cnt[p] = 0;
    const int lim = bid * TPB;
    for (int i = tid; i < lim; i += 256) {
        int2 c = choices[i];
        #pragma unroll
        for (int p = 0; p < 8; ++p) {
            cnt[p]     += (c.x == p);
            cnt[8 + p] += (c.y == p);
        }
    }
    #pragma unroll
    for (int off = 1; off < 64; off <<= 1) {
        #pragma unroll
        for (int p = 0; p < 16; ++p)
            cnt[p] += __shfl_xor(cnt[p], off, 64);
    }
    if (lane == 0) {
        #pragma unroll
        for (int p = 0; p < 16; ++p) partial[wv][p] = cnt[p];
    }
    __syncthreads();
    if (tid < 16)
        base[tid] = partial[0][tid] + partial[1][tid] +
                    partial[2][tid] + partial[3][tid];
    __syncthreads();

    // ---- B: targets for this block's 4 tokens ---------------------------
    if (tid == 0) {
        int2 c[TPB];
        #pragma unroll
        for (int t = 0; t < TPB; ++t) c[t] = choices[bid * TPB + t];
        #pragma unroll
        for (int t = 0; t < TPB; ++t) {
            const int e0 = c[t].x;
            unsigned r = 0;
            #pragma unroll
            for (int m = 0; m < TPB; ++m) if (m < t) r += (c[m].x == e0);
            unsigned p0 = base[e0] + r;
            tg[t * 2 + 0] = (p0 < CAP) ? ((t * NE + e0) * CAP + (int)p0) : -1;

            const int e1 = c[t].y;
            r = 0;
            #pragma unroll
            for (int m = 0; m < TPB; ++m) if (m < t) r += (c[m].y == e1);
            unsigned p1 = base[8 + e1] + r;
            tg[t * 2 + 1] = (p1 < CAP) ? ((t * NE + e1) * CAP + (int)p1) : -1;
        }
    }

    // ---- C: zero slice, then patch --------------------------------------
    {
        float4 z = make_float4(0.f, 0.f, 0.f, 0.f);
        float4* dp = reinterpret_cast<float4*>(out) + (size_t)bid * (SLICE / 4);
        #pragma unroll
        for (int i = 0; i < (SLICE / 4) / 256; ++i)            // 16
            dp[i * 256 + tid] = z;
    }
    __syncthreads();
    if (tid < TPB * 2) {
        const int g = tg[tid];
        if (g >= 0) out[(size_t)bid * SLICE + g] = 1.0f;
    }
}

extern "C" void kernel_launch(void* const* d_in, const int* in_sizes, int n_in,
                              void* d_out, int out_size, void* d_ws, size_t ws_size,
                              hipStream_t stream) {
    const float* x = (const float*)d_in[0];
    const float* W = (const float*)d_in[1];
    float* out     = (float*)d_out;
    int2* choices  = (int2*)d_ws;     // 32 KB

    hipLaunchKernelGGL(k_logits3, dim3(NLB), dim3(256), 0, stream,
                       x, W, out, choices);
    hipLaunchKernelGGL(k_finish,  dim3(NFB), dim3(256), 0, stream,
                       choices, out);
}